// Round 9
// baseline (184.295 us; speedup 1.0000x reference)
//
#include <hip/hip_runtime.h>

typedef float f32x4 __attribute__((ext_vector_type(4)));
typedef unsigned short u16x8 __attribute__((ext_vector_type(8)));
typedef __bf16 bf16x8 __attribute__((ext_vector_type(8)));

// ---------------------------------------------------------------------------
// Kernel 1: convert + transpose three W (fp32 [256 k][512 n]) into bf16 W^T
// [role][512 n][256 k] in workspace, via 64x64 LDS tile transpose.
// ---------------------------------------------------------------------------
__global__ __launch_bounds__(256) void convert_w_kernel(
    const float* __restrict__ Wt_, const float* __restrict__ Wi_,
    const float* __restrict__ Wo_, unsigned short* __restrict__ out)
{
    __shared__ unsigned short tile[64][72];

    const int b    = blockIdx.x;
    const int role = b >> 5;
    const int kt   = (b & 31) >> 3;
    const int nt   = b & 7;
    const float* __restrict__ W = (role == 0) ? Wt_ : ((role == 1) ? Wi_ : Wo_);

    const int t  = threadIdx.x;
    const int r0 = t >> 4;
    const int c4 = (t & 15) << 2;

#pragma unroll
    for (int j = 0; j < 4; ++j) {
        const int kl = r0 + j * 16;
        f32x4 v = *(const f32x4*)(W + (size_t)(kt * 64 + kl) * 512 + nt * 64 + c4);
#pragma unroll
        for (int e = 0; e < 4; ++e)
            tile[c4 + e][kl] = __builtin_bit_cast(unsigned short, (__bf16)v[e]);
    }
    __syncthreads();

    const int cs = t & 7;
#pragma unroll
    for (int p = 0; p < 2; ++p) {
        const int r = (t >> 3) + p * 32;
        u16x8 v = *(const u16x8*)&tile[r][cs * 8];
        *(u16x8*)(out + (size_t)role * 512 * 256 +
                  (size_t)(nt * 64 + r) * 256 + kt * 64 + cs * 8) = v;
    }
}

// ---------------------------------------------------------------------------
// Kernel 2: TRUE STREAMING role-GEMM. No LDS, no barriers, no cross-lane
// data movement. Wave = 32 exclusive rows x 512 cols. With swapped MFMA
// operands, act-row maps to lane&15, so each lane loads its OWN row's
// contiguous 32 B k-chunks straight into registers (instruction pairs
// cover full 128 B lines; cached so the sibling half hits L1). Then 32
// n-strips: 8 W-fragment loads (L1/L2-hot) -> 16 MFMA (x2 row-group reuse)
// -> 2 bias+store instructions (cached; L2 merges 64 B halves into full
// lines). 16 independent waves/CU at staggered phases keep read+write
// streams continuously fed -- the copy-kernel regime that hits 6.3 TB/s.
// Rounds 1-8 all had block-wide read/compute/write phases capping HBM
// duty at ~50% (3.3 TB/s across 7 different schedules).
// ---------------------------------------------------------------------------
__global__ __launch_bounds__(256, 4) void role_proj_kernel(
    const float* __restrict__ A,            // [131072][256] fp32
    const int* __restrict__ tmask,          // [64]
    const int* __restrict__ imask,          // [64]
    const unsigned short* __restrict__ Wws, // [3][512][256] bf16 (W^T)
    const float* __restrict__ bt, const float* __restrict__ bi,
    const float* __restrict__ bo,
    float* __restrict__ C)                  // [131072][512] fp32
{
    const int tid  = threadIdx.x;
    const int lane = tid & 63;
    const int wid  = tid >> 6;                  // 0..3
    const int l15  = lane & 15;
    const int l4   = lane >> 4;                 // 0..3

    // wave owns rows [m0w, m0w+32); block = 128 rows (role uniform: mask
    // index = row/2048 -> blockIdx/16)
    const int m0w  = blockIdx.x * 128 + wid * 32;
    const int mi   = blockIdx.x >> 4;
    const int role = tmask[mi] ? 0 : (imask[mi] ? 1 : 2);
    const unsigned short* __restrict__ W = Wws + (size_t)role * (512 * 256);
    const float* __restrict__ bias = (role == 0) ? bt : ((role == 1) ? bi : bo);

    // ---- load this wave's A rows straight into registers, convert to bf16.
    // Lane (l15,l4), group g: row m0w+g*16+l15, k in [ks*32+l4*8, +8).
    // Per (g,ks): 4 l4-lanes x 32 B = one full 128 B line per row; the two
    // f32x4 halves are back-to-back so the second hits L1.
    const float* a0 = A + (size_t)(m0w + l15) * 256 + l4 * 8;
    const float* a1 = a0 + 16 * 256;

    bf16x8 abf[2][8];
#pragma unroll
    for (int ks = 0; ks < 8; ++ks) {
        f32x4 t00 = *(const f32x4*)(a0 + ks * 32);
        f32x4 t01 = *(const f32x4*)(a0 + ks * 32 + 4);
        f32x4 t10 = *(const f32x4*)(a1 + ks * 32);
        f32x4 t11 = *(const f32x4*)(a1 + ks * 32 + 4);
        bf16x8 p0 = { (__bf16)t00[0], (__bf16)t00[1], (__bf16)t00[2], (__bf16)t00[3],
                      (__bf16)t01[0], (__bf16)t01[1], (__bf16)t01[2], (__bf16)t01[3] };
        bf16x8 p1 = { (__bf16)t10[0], (__bf16)t10[1], (__bf16)t10[2], (__bf16)t10[3],
                      (__bf16)t11[0], (__bf16)t11[1], (__bf16)t11[2], (__bf16)t11[3] };
        abf[0][ks] = p0;
        abf[1][ks] = p1;
    }

    // ---- stream over 32 n-strips of 16 channels each.
    const size_t crow0 = (size_t)(m0w + l15) * 512;
    const size_t crow1 = crow0 + (size_t)16 * 512;

#pragma unroll 1
    for (int fn = 0; fn < 32; ++fn) {
        const unsigned short* wp =
            W + (size_t)(fn * 16 + l15) * 256 + l4 * 8;

        u16x8 bfr[8];
#pragma unroll
        for (int ks = 0; ks < 8; ++ks)
            bfr[ks] = *(const u16x8*)(wp + ks * 32);   // L1/L2-resident

        f32x4 acc0 = {};
        f32x4 acc1 = {};
#pragma unroll
        for (int ks = 0; ks < 8; ++ks) {
            // swapped operands: D row = out-channel (l4*4 + reg -> 4
            // consecutive channels per lane), D col = act row (l15)
            acc0 = __builtin_amdgcn_mfma_f32_16x16x32_bf16(
                __builtin_bit_cast(bf16x8, bfr[ks]), abf[0][ks], acc0, 0, 0, 0);
            acc1 = __builtin_amdgcn_mfma_f32_16x16x32_bf16(
                __builtin_bit_cast(bf16x8, bfr[ks]), abf[1][ks], acc1, 0, 0, 0);
        }

        const int col = fn * 16 + l4 * 4;
        const f32x4 bv = *(const f32x4*)(bias + col);   // L1-hot (2 KB)
        *(f32x4*)(C + crow0 + col) = acc0 + bv;         // cached: L2 merges
        *(f32x4*)(C + crow1 + col) = acc1 + bv;         //   64 B half-lines
    }
}

extern "C" void kernel_launch(void* const* d_in, const int* in_sizes, int n_in,
                              void* d_out, int out_size, void* d_ws, size_t ws_size,
                              hipStream_t stream) {
    const float* A   = (const float*)d_in[0];
    const int*   tm  = (const int*)d_in[1];
    const int*   im  = (const int*)d_in[2];
    const float* Wt_ = (const float*)d_in[3];
    const float* bt  = (const float*)d_in[4];
    const float* Wi_ = (const float*)d_in[5];
    const float* bi  = (const float*)d_in[6];
    const float* Wo_ = (const float*)d_in[7];
    const float* bo  = (const float*)d_in[8];

    unsigned short* Wws = (unsigned short*)d_ws;   // 3*512*256*2 = 768 KB

    hipLaunchKernelGGL(convert_w_kernel, dim3(96), dim3(256),
                       0, stream, Wt_, Wi_, Wo_, Wws);

    hipLaunchKernelGGL(role_proj_kernel, dim3(1024), dim3(256),
                       0, stream, A, tm, im, Wws, bt, bi, bo, (float*)d_out);
}

// Round 10
// 113.177 us; speedup vs baseline: 1.6284x; 1.6284x over previous
//
#include <hip/hip_runtime.h>

typedef float f32x4 __attribute__((ext_vector_type(4)));
typedef unsigned short u16x8 __attribute__((ext_vector_type(8)));
typedef __bf16 bf16x8 __attribute__((ext_vector_type(8)));
typedef __bf16 bf16x4 __attribute__((ext_vector_type(4)));

// ---------------------------------------------------------------------------
// Kernel 1: convert + transpose three W (fp32 [256 k][512 n]) into bf16 W^T
// [role][512 n][256 k] in workspace, via 64x64 LDS tile transpose.
// ---------------------------------------------------------------------------
__global__ __launch_bounds__(256) void convert_w_kernel(
    const float* __restrict__ Wt_, const float* __restrict__ Wi_,
    const float* __restrict__ Wo_, unsigned short* __restrict__ out)
{
    __shared__ unsigned short tile[64][72];

    const int b    = blockIdx.x;
    const int role = b >> 5;
    const int kt   = (b & 31) >> 3;
    const int nt   = b & 7;
    const float* __restrict__ W = (role == 0) ? Wt_ : ((role == 1) ? Wi_ : Wo_);

    const int t  = threadIdx.x;
    const int r0 = t >> 4;
    const int c4 = (t & 15) << 2;

#pragma unroll
    for (int j = 0; j < 4; ++j) {
        const int kl = r0 + j * 16;
        f32x4 v = *(const f32x4*)(W + (size_t)(kt * 64 + kl) * 512 + nt * 64 + c4);
#pragma unroll
        for (int e = 0; e < 4; ++e)
            tile[c4 + e][kl] = __builtin_bit_cast(unsigned short, (__bf16)v[e]);
    }
    __syncthreads();

    const int cs = t & 7;
#pragma unroll
    for (int p = 0; p < 2; ++p) {
        const int r = (t >> 3) + p * 32;
        u16x8 v = *(const u16x8*)&tile[r][cs * 8];
        *(u16x8*)(out + (size_t)role * 512 * 256 +
                  (size_t)(nt * 64 + r) * 256 + kt * 64 + cs * 8) = v;
    }
}

// ---------------------------------------------------------------------------
// Kernel 2: R8 structure (120 us: full-density loads, one barrier,
// wave-private barrier-free epilogue, NT full-line stores) with ONE change:
// A staging loads are CACHED, not nontemporal. R9's counters proved A
// (134 MB < 256 MB L3) stays partially L3-resident ACROSS GRAPH REPLAYS
// when loaded cached (FETCH_SIZE 69 MB vs 149 MB with NT loads). NT C
// stores keep L3 clean for A. Expected: hbm_bytes 402 -> ~310-340 MB.
// ---------------------------------------------------------------------------
__global__ __launch_bounds__(512, 4) void role_proj_kernel(
    const float* __restrict__ A,            // [131072][256] fp32
    const int* __restrict__ tmask,          // [64]
    const int* __restrict__ imask,          // [64]
    const unsigned short* __restrict__ Wws, // [3][512][256] bf16 (W^T)
    const float* __restrict__ bt, const float* __restrict__ bi,
    const float* __restrict__ bo,
    float* __restrict__ C)                  // [131072][512] fp32
{
    // [0,32K): bf16 A tile (staging/compute). [32K,64K): 8 x 4 KB wave scratch.
    __shared__ __align__(16) unsigned char smem[64 * 1024];
    unsigned short* As = (unsigned short*)smem;

    const int tid = threadIdx.x;
    const int m0  = blockIdx.x * 64;

    // role uniform per block: mask index = t/32 = blockIdx/32
    const int mi   = blockIdx.x >> 5;
    const int role = tmask[mi] ? 0 : (imask[mi] ? 1 : 2);
    const unsigned short* __restrict__ W = Wws + (size_t)role * (512 * 256);
    const float* __restrict__ bias = (role == 0) ? bt : ((role == 1) ? bi : bo);

    // ---- Phase 1: stage A (64 x 256 fp32 = 64 KB), full-density CACHED
    // loads (L3-resident across replays). Instruction p: 64 lanes x
    // consecutive 16 B = 1 KB contiguous.
    const f32x4* abase = (const f32x4*)(A + (size_t)m0 * 256);
    f32x4 ld[8];
#pragma unroll
    for (int p = 0; p < 8; ++p)
        ld[p] = abase[tid + 512 * p];
#pragma unroll
    for (int p = 0; p < 8; ++p) {
        const int u    = tid + 512 * p;       // float4-unit index in tile
        const int row  = u >> 6;              // 64 units per 256-float row
        const int slot = ((u & 63) >> 1) ^ (row & 7);   // 16 B slot, swizzled
        bf16x4 pk = { (__bf16)ld[p][0], (__bf16)ld[p][1],
                      (__bf16)ld[p][2], (__bf16)ld[p][3] };
        *(bf16x4*)(smem + row * 512 + slot * 16 + (u & 1) * 8) = pk;
    }
    __syncthreads();   // the ONLY barrier in the block

    // ---- Phase 2: compute. Wave = 64 rows x 64 cols (wid strip).
    const int lane  = tid & 63;
    const int wid   = tid >> 6;
    const int l15   = lane & 15;
    const int l4    = lane >> 4;
    const int nbase = wid * 64;
    const int r7    = l15 & 7;

    const unsigned short* wp[4];
#pragma unroll
    for (int fn = 0; fn < 4; ++fn)
        wp[fn] = W + (size_t)(nbase + fn * 16 + l15) * 256 + l4 * 8;

    f32x4 acc[4][4] = {};          // [fm][fn]

#pragma unroll 1
    for (int ks = 0; ks < 8; ++ks) {
        u16x8 bfr[4];
#pragma unroll
        for (int fn = 0; fn < 4; ++fn)
            bfr[fn] = *(const u16x8*)(wp[fn] + ks * 32);   // L1/L2-resident
        u16x8 afr[4];
#pragma unroll
        for (int fm = 0; fm < 4; ++fm) {
            const int row  = fm * 16 + l15;
            const int slot = (ks * 4 + l4) ^ r7;
            afr[fm] = *(const u16x8*)&As[row * 256 + slot * 8];
        }
#pragma unroll
        for (int fm = 0; fm < 4; ++fm) {
#pragma unroll
            for (int fn = 0; fn < 4; ++fn) {
                // swapped operands: acc row = out-channel (4 consecutive per
                // lane via reg idx), col = activation row
                acc[fm][fn] = __builtin_amdgcn_mfma_f32_16x16x32_bf16(
                    __builtin_bit_cast(bf16x8, bfr[fn]),
                    __builtin_bit_cast(bf16x8, afr[fm]),
                    acc[fm][fn], 0, 0, 0);
            }
        }
    }

    // ---- Phase 3: wave-private epilogue, NO barriers.
    // Scratch: this wave's 4 KB = [16 act-rows][64 ch] fp32, 16 B-unit XOR
    // swizzle to spread banks. Same-wave ds ordering guaranteed by data deps.
    unsigned char* cs = smem + 32768 + wid * 4096;

    f32x4 bv[4];
#pragma unroll
    for (int fn = 0; fn < 4; ++fn)
        bv[fn] = *(const f32x4*)(bias + nbase + fn * 16 + l4 * 4);

#pragma unroll
    for (int fm = 0; fm < 4; ++fm) {
        // write acc slice: row = l15, 16B-unit g = fn*4+l4, swizzled by row
#pragma unroll
        for (int fn = 0; fn < 4; ++fn) {
            const int g = (fn * 4 + l4) ^ r7;
            *(f32x4*)(cs + l15 * 256 + g * 16) = acc[fm][fn] + bv[fn];
        }
        // read lane-linear + NT store: 4 rows x 256 B contiguous per instr
#pragma unroll
        for (int q = 0; q < 4; ++q) {
            const int r = (lane >> 4) + 4 * q;           // act-row 0..15
            const int g = (lane & 15) ^ (r & 7);         // swizzled 16B unit
            f32x4 v = *(const f32x4*)(cs + r * 256 + g * 16);
            __builtin_nontemporal_store(
                v, (f32x4*)(C + (size_t)(m0 + fm * 16 + r) * 512 +
                            nbase + (lane & 15) * 4));
        }
    }
}

extern "C" void kernel_launch(void* const* d_in, const int* in_sizes, int n_in,
                              void* d_out, int out_size, void* d_ws, size_t ws_size,
                              hipStream_t stream) {
    const float* A   = (const float*)d_in[0];
    const int*   tm  = (const int*)d_in[1];
    const int*   im  = (const int*)d_in[2];
    const float* Wt_ = (const float*)d_in[3];
    const float* bt  = (const float*)d_in[4];
    const float* Wi_ = (const float*)d_in[5];
    const float* bi  = (const float*)d_in[6];
    const float* Wo_ = (const float*)d_in[7];
    const float* bo  = (const float*)d_in[8];

    unsigned short* Wws = (unsigned short*)d_ws;   // 3*512*256*2 = 768 KB

    hipLaunchKernelGGL(convert_w_kernel, dim3(96), dim3(256),
                       0, stream, Wt_, Wi_, Wo_, Wws);

    hipLaunchKernelGGL(role_proj_kernel, dim3(2048), dim3(512),
                       0, stream, A, tm, im, Wws, bt, bi, bo, (float*)d_out);
}